// Round 8
// baseline (443.919 us; speedup 1.0000x reference)
//
#include <hip/hip_runtime.h>
#include <hip/hip_bf16.h>

#define BDIM 8192
#define DDIM 256

typedef __attribute__((ext_vector_type(8))) short  s16x8;   // 8 x bf16 (4 VGPRs)
typedef __attribute__((ext_vector_type(4))) float  f32x4;   // MFMA accumulator
typedef __attribute__((ext_vector_type(4))) float  fv4;     // clang vector (nontemporal-ok)

__device__ inline ushort f2bf(float x) {
    __hip_bfloat16 h = __float2bfloat16(x);
    ushort u;
    __builtin_memcpy(&u, &h, 2);
    return u;
}

__device__ __forceinline__ uint2 pack4(fv4 v) {
    uint2 r;
    r.x = f2bf(v.x) | ((unsigned)f2bf(v.y) << 16);
    r.y = f2bf(v.z) | ((unsigned)f2bf(v.w) << 16);
    return r;
}

// ---------------------------------------------------------------------------
// Kernel A: per-row stats + fragment-swizzled bf16 a_hat (layout-1).
//   u16 index(row,d) = (row>>4)*4096 + (d>>5)*512 + ((d>>3)&3)*128
//                      + (row&15)*8 + (d&7)      (verified: absmax 0.0)
// ---------------------------------------------------------------------------
__global__ __launch_bounds__(256) void row_stats(
    const float* __restrict__ A, const float* __restrict__ P,
    const float* __restrict__ N, ushort* __restrict__ Asw,
    float* __restrict__ partial_trip)
{
    __shared__ float tsh[4];
    const int wave = threadIdx.x >> 6;
    const int lane = threadIdx.x & 63;
    const int row  = blockIdx.x * 4 + wave;

    const float4 a = *(reinterpret_cast<const float4*>(A + (size_t)row * DDIM) + lane);
    const float4 p = *(reinterpret_cast<const float4*>(P + (size_t)row * DDIM) + lane);
    const float4 n = *(reinterpret_cast<const float4*>(N + (size_t)row * DDIM) + lane);

    float sa = a.x*a.x + a.y*a.y + a.z*a.z + a.w*a.w;

    float d0 = a.x - p.x + 1e-6f, d1 = a.y - p.y + 1e-6f;
    float d2 = a.z - p.z + 1e-6f, d3 = a.w - p.w + 1e-6f;
    float sp = d0*d0 + d1*d1 + d2*d2 + d3*d3;

    d0 = a.x - n.x + 1e-6f; d1 = a.y - n.y + 1e-6f;
    d2 = a.z - n.z + 1e-6f; d3 = a.w - n.w + 1e-6f;
    float sn = d0*d0 + d1*d1 + d2*d2 + d3*d3;

    #pragma unroll
    for (int off = 32; off > 0; off >>= 1) {
        sa += __shfl_xor(sa, off);
        sp += __shfl_xor(sp, off);
        sn += __shfl_xor(sn, off);
    }

    const float inv = 1.0f / fmaxf(sqrtf(sa), 1e-8f);

    ushort4 hv;
    hv.x = f2bf(a.x * inv);
    hv.y = f2bf(a.y * inv);
    hv.z = f2bf(a.z * inv);
    hv.w = f2bf(a.w * inv);
    const size_t chunk = ((size_t)(row >> 4) * 8 + (lane >> 3)) * 64
                       + (size_t)(((lane >> 1) & 3) * 16 + (row & 15));
    *reinterpret_cast<ushort4*>(Asw + chunk * 8 + (lane & 1) * 4) = hv;

    if (lane == 0)
        tsh[wave] = fmaxf(sqrtf(sp) - sqrtf(sn) + 0.2f, 0.0f);
    __syncthreads();
    if (threadIdx.x == 0)
        partial_trip[blockIdx.x] = tsh[0] + tsh[1] + tsh[2] + tsh[3];
}

// ---------------------------------------------------------------------------
// Kernel T: layout-2 (A_hat^T fragment chunks) from layout-1.
//   u16 base((d0>>4),(j0>>5)) = ((d0>>4)*256 + (j0>>5))*512; lane l holds
//   A_hat[j0 + (l>>4)*8 + jj][d0 + (l&15)], jj=0..7 -> 1KB coalesced frag.
// ---------------------------------------------------------------------------
__global__ __launch_bounds__(256) void transpose_ahat(
    const ushort* __restrict__ Asw, ushort* __restrict__ Asw2)
{
    const int t = threadIdx.x, w = t >> 6, lane = t & 63;
    const int fr = lane & 15, kg = lane >> 4;
    const int b = blockIdx.x;                 // 64 blocks
    const int j0 = b * 128 + w * 32;

    #pragma unroll 1
    for (int D = 0; D < 16; ++D) {
        const int d = D * 16 + fr;
        ushort v[8];
        #pragma unroll
        for (int jj = 0; jj < 8; ++jj) {
            const int J = j0 + kg * 8 + jj;
            v[jj] = Asw[(size_t)(J >> 4) * 4096 + (d >> 5) * 512
                        + ((d >> 3) & 3) * 128 + (J & 15) * 8 + (d & 7)];
        }
        uint4 pk;
        pk.x = v[0] | ((unsigned)v[1] << 16);
        pk.y = v[2] | ((unsigned)v[3] << 16);
        pk.z = v[4] | ((unsigned)v[5] << 16);
        pk.w = v[6] | ((unsigned)v[7] << 16);
        *reinterpret_cast<uint4*>(
            Asw2 + (size_t)(D * 256 + b * 4 + w) * 512 + (size_t)lane * 8) = pk;
    }
}

// ---------------------------------------------------------------------------
// Kernel G: Gram partials  M = A_hat^T A_hat (256x256), K split in 32 chunks.
// ---------------------------------------------------------------------------
__global__ __launch_bounds__(256, 2) void gram(
    const ushort* __restrict__ Asw2, float* __restrict__ Mpart)
{
    const int t = threadIdx.x, w = t >> 6, lane = t & 63;
    const int fr = lane & 15, kg = lane >> 4;
    const int kc = blockIdx.x;   // 0..31
    const int h  = blockIdx.y;   // 0..1

    f32x4 acc[8][4] = {};
    #pragma unroll 1
    for (int k32 = 0; k32 < 8; ++k32) {
        const int j5 = (kc * 256 + k32 * 32) >> 5;
        s16x8 af[8], bf[4];
        #pragma unroll
        for (int m = 0; m < 8; ++m)
            af[m] = *reinterpret_cast<const s16x8*>(
                Asw2 + ((size_t)((h * 8 + m) * 256 + j5)) * 512 + lane * 8);
        #pragma unroll
        for (int n = 0; n < 4; ++n)
            bf[n] = *reinterpret_cast<const s16x8*>(
                Asw2 + ((size_t)((w * 4 + n) * 256 + j5)) * 512 + lane * 8);
        #pragma unroll
        for (int m = 0; m < 8; ++m)
            #pragma unroll
            for (int n = 0; n < 4; ++n)
                acc[m][n] = __builtin_amdgcn_mfma_f32_16x16x32_bf16(
                    af[m], bf[n], acc[m][n], 0, 0, 0);
    }
    float* base = Mpart + (size_t)kc * 65536
                + (size_t)(h * 128 + kg * 4) * 256 + w * 64 + fr;
    #pragma unroll
    for (int m = 0; m < 8; ++m)
        #pragma unroll
        for (int reg = 0; reg < 4; ++reg)
            #pragma unroll
            for (int n = 0; n < 4; ++n)
                base[(size_t)(m * 16 + reg) * 256 + n * 16] = acc[m][n][reg];
}

__global__ __launch_bounds__(256) void gram_reduce(
    const float* __restrict__ Mpart, float* __restrict__ gpart)
{
    __shared__ float sh[4];
    const int t = threadIdx.x;
    const int id = blockIdx.x * 256 + t;
    float ss = 0.f;
    for (int e = id; e < 65536; e += 16384) {
        float s = 0.f;
        #pragma unroll 4
        for (int kc = 0; kc < 32; ++kc)
            s += Mpart[(size_t)kc * 65536 + e];
        ss += s * s;
    }
    #pragma unroll
    for (int off = 32; off > 0; off >>= 1) ss += __shfl_down(ss, off);
    const int w = t >> 6, lane = t & 63;
    if (lane == 0) sh[w] = ss;
    __syncthreads();
    if (t == 0) gpart[blockIdx.x] = sh[0] + sh[1] + sh[2] + sh[3];
}

// ---------------------------------------------------------------------------
// Kernel D: trace(S * cos) partials + sum(S^2), streaming S once.
// 512 blocks (2/CU), 512 thr. Block: 128 M-rows (ti), 1024 K-cols (c0),
// 16 rounds of 64 cols. Spill-proof: named regs only, no lambdas/asm.
// Round: [B-frags (L2, issued FIRST)] -> [S regs for r+1 (HBM, NT)] ->
//        [MFMA on sbuf[r&1]] -> [pack S(r+1) -> sbuf[(r+1)&1], fused S^2]
//        -> __syncthreads (everything already consumed; drain is free).
// Epilogue: dot(acc, A_hat layout-1 gathers) -> dotp/s2p.
// ---------------------------------------------------------------------------
__global__ __launch_bounds__(512) void s_dot(
    const float* __restrict__ S, const ushort* __restrict__ Asw,
    const ushort* __restrict__ Asw2,
    float* __restrict__ dotp, float* __restrict__ s2p)
{
    __shared__ ushort sbuf[2][128 * 64];   // 2 x 16 KB bf16, XOR-swizzled
    __shared__ float red[16];

    const int t = threadIdx.x;             // 0..511
    const int w = t >> 6, lane = t & 63;
    const int fr = lane & 15, kg = lane >> 4;

    const int bid = blockIdx.x;            // 0..511
    const int ti  = (bid >> 3) * 128;      // 64 i-tiles
    const int c0  = (bid & 7) * 1024;      // 8 k-chunks (-> XCD = bid&7)

    const int srow = t >> 2, sq = t & 3;   // staging: row t>>2, quad t&3
    const int sw   = srow & 7;
    const float* sg = S + (size_t)(ti + srow) * BDIM + c0 + sq * 4;

    const int x0 = kg ^ (fr & 7);          // kk=0 read chunk
    const int x1 = (4 + kg) ^ (fr & 7);    // kk=1 read chunk

    float s2_local = 0.f;
    f32x4 acc[8][2] = {};

    // ---- prologue: stage round 0
    {
        fv4 v0 = __builtin_nontemporal_load(reinterpret_cast<const fv4*>(sg));
        fv4 v1 = __builtin_nontemporal_load(reinterpret_cast<const fv4*>(sg + 16));
        fv4 v2 = __builtin_nontemporal_load(reinterpret_cast<const fv4*>(sg + 32));
        fv4 v3 = __builtin_nontemporal_load(reinterpret_cast<const fv4*>(sg + 48));
        ushort* dst = &sbuf[0][srow * 64];
        *reinterpret_cast<uint2*>(dst + ((((sq >> 1) + 0) ^ sw) * 8) + (sq & 1) * 4) = pack4(v0);
        *reinterpret_cast<uint2*>(dst + ((((sq >> 1) + 2) ^ sw) * 8) + (sq & 1) * 4) = pack4(v1);
        *reinterpret_cast<uint2*>(dst + ((((sq >> 1) + 4) ^ sw) * 8) + (sq & 1) * 4) = pack4(v2);
        *reinterpret_cast<uint2*>(dst + ((((sq >> 1) + 6) ^ sw) * 8) + (sq & 1) * 4) = pack4(v3);
        s2_local += v0.x*v0.x + v0.y*v0.y + v0.z*v0.z + v0.w*v0.w
                  + v1.x*v1.x + v1.y*v1.y + v1.z*v1.z + v1.w*v1.w
                  + v2.x*v2.x + v2.y*v2.y + v2.z*v2.z + v2.w*v2.w
                  + v3.x*v3.x + v3.y*v3.y + v3.z*v3.z + v3.w*v3.w;
    }
    __syncthreads();

    for (int r = 0; r < 16; ++r) {
        // ---- B-frags for this round: issued FIRST (L2; waits on these
        //      never drain the younger HBM S-loads -- vmcnt is in-order)
        const int j5 = (c0 + r * 64) >> 5;
        const s16x8 b0 = *reinterpret_cast<const s16x8*>(
            Asw2 + ((size_t)((w * 2 + 0) * 256 + j5)) * 512 + lane * 8);
        const s16x8 b1 = *reinterpret_cast<const s16x8*>(
            Asw2 + ((size_t)((w * 2 + 1) * 256 + j5)) * 512 + lane * 8);
        const s16x8 b2 = *reinterpret_cast<const s16x8*>(
            Asw2 + ((size_t)((w * 2 + 0) * 256 + j5 + 1)) * 512 + lane * 8);
        const s16x8 b3 = *reinterpret_cast<const s16x8*>(
            Asw2 + ((size_t)((w * 2 + 1) * 256 + j5 + 1)) * 512 + lane * 8);
        __builtin_amdgcn_sched_barrier(0);

        // ---- S loads for round r+1 (HBM, land during MFMA+stage)
        fv4 v0, v1, v2, v3;
        if (r < 15) {
            const float* p = sg + (size_t)(r + 1) * 64;
            v0 = __builtin_nontemporal_load(reinterpret_cast<const fv4*>(p));
            v1 = __builtin_nontemporal_load(reinterpret_cast<const fv4*>(p + 16));
            v2 = __builtin_nontemporal_load(reinterpret_cast<const fv4*>(p + 32));
            v3 = __builtin_nontemporal_load(reinterpret_cast<const fv4*>(p + 48));
        }
        __builtin_amdgcn_sched_barrier(0);

        // ---- MFMA on current buffer
        const ushort* sb = sbuf[r & 1];
        #pragma unroll
        for (int m = 0; m < 8; ++m) {
            const int R = m * 16 + fr;
            const s16x8 a0 = *reinterpret_cast<const s16x8*>(sb + R * 64 + x0 * 8);
            const s16x8 a1 = *reinterpret_cast<const s16x8*>(sb + R * 64 + x1 * 8);
            acc[m][0] = __builtin_amdgcn_mfma_f32_16x16x32_bf16(a0, b0, acc[m][0], 0, 0, 0);
            acc[m][1] = __builtin_amdgcn_mfma_f32_16x16x32_bf16(a0, b1, acc[m][1], 0, 0, 0);
            acc[m][0] = __builtin_amdgcn_mfma_f32_16x16x32_bf16(a1, b2, acc[m][0], 0, 0, 0);
            acc[m][1] = __builtin_amdgcn_mfma_f32_16x16x32_bf16(a1, b3, acc[m][1], 0, 0, 0);
        }

        // ---- stage S(r+1) into the other buffer, fused S^2
        if (r < 15) {
            ushort* dst = &sbuf[(r + 1) & 1][srow * 64];
            *reinterpret_cast<uint2*>(dst + ((((sq >> 1) + 0) ^ sw) * 8) + (sq & 1) * 4) = pack4(v0);
            *reinterpret_cast<uint2*>(dst + ((((sq >> 1) + 2) ^ sw) * 8) + (sq & 1) * 4) = pack4(v1);
            *reinterpret_cast<uint2*>(dst + ((((sq >> 1) + 4) ^ sw) * 8) + (sq & 1) * 4) = pack4(v2);
            *reinterpret_cast<uint2*>(dst + ((((sq >> 1) + 6) ^ sw) * 8) + (sq & 1) * 4) = pack4(v3);
            s2_local += v0.x*v0.x + v0.y*v0.y + v0.z*v0.z + v0.w*v0.w
                      + v1.x*v1.x + v1.y*v1.y + v1.z*v1.z + v1.w*v1.w
                      + v2.x*v2.x + v2.y*v2.y + v2.z*v2.z + v2.w*v2.w
                      + v3.x*v3.x + v3.y*v3.y + v3.z*v3.z + v3.w*v3.w;
        }
        __syncthreads();
    }

    // ---- epilogue: dot(acc, A_hat); row = ti+m*16+kg*4+reg, col = w*32+n*16+fr
    float dot_local = 0.f;
    #pragma unroll 1
    for (int m = 0; m < 8; ++m) {
        #pragma unroll
        for (int n = 0; n < 2; ++n) {
            const int d = w * 32 + n * 16 + fr;
            const size_t abase = (size_t)((ti >> 4) + m) * 4096
                               + (d >> 5) * 512 + ((d >> 3) & 3) * 128 + (d & 7);
            #pragma unroll
            for (int reg = 0; reg < 4; ++reg) {
                const ushort u = Asw[abase + (kg * 4 + reg) * 8];
                dot_local += __uint_as_float((unsigned)u << 16) * acc[m][n][reg];
            }
        }
    }

    #pragma unroll
    for (int off = 32; off > 0; off >>= 1) {
        dot_local += __shfl_down(dot_local, off);
        s2_local  += __shfl_down(s2_local, off);
    }
    if (lane == 0) { red[w] = dot_local; red[8 + w] = s2_local; }
    __syncthreads();
    if (t == 0) {
        float da = 0.f, sb2 = 0.f;
        #pragma unroll
        for (int i = 0; i < 8; ++i) { da += red[i]; sb2 += red[8 + i]; }
        dotp[bid] = da;
        s2p[bid]  = sb2;
    }
}

// ---------------------------------------------------------------------------
// finalize: out = trip/B + (gram_ss - 2*dot + s2) / B^2
// ---------------------------------------------------------------------------
__global__ __launch_bounds__(256) void finalize(
    const float* __restrict__ pt, const float* __restrict__ dotp,
    const float* __restrict__ s2p, const float* __restrict__ gpart,
    float* __restrict__ out)
{
    __shared__ float sh[4];
    const int t = threadIdx.x;
    float trip = 0.f, sim = 0.f;
    for (int i = t; i < 2048; i += 256) trip += pt[i];
    for (int i = t; i < 512; i += 256) sim += -2.f * dotp[i] + s2p[i];
    if (t < 64) sim += gpart[t];
    float v = trip * (1.0f / (float)BDIM)
            + sim  * (1.0f / ((float)BDIM * (float)BDIM));
    #pragma unroll
    for (int off = 32; off > 0; off >>= 1) v += __shfl_down(v, off);
    const int w = t >> 6, lane = t & 63;
    if (lane == 0) sh[w] = v;
    __syncthreads();
    if (t == 0) out[0] = sh[0] + sh[1] + sh[2] + sh[3];
}

extern "C" void kernel_launch(void* const* d_in, const int* in_sizes, int n_in,
                              void* d_out, int out_size, void* d_ws, size_t ws_size,
                              hipStream_t stream)
{
    const float* anchor   = (const float*)d_in[0];
    const float* positive = (const float*)d_in[1];
    const float* negative = (const float*)d_in[2];
    const float* S        = (const float*)d_in[3];
    float* out = (float*)d_out;

    float*  pt    = (float*)d_ws;                          // 2048 f
    float*  dotp  = (float*)((char*)d_ws + 8192);          // 512 f
    float*  s2p   = (float*)((char*)d_ws + 12288);         // 512 f
    float*  gpart = (float*)((char*)d_ws + 16384);         // 64 f
    ushort* Asw   = (ushort*)((char*)d_ws + (1u  << 20));  // 4 MB layout-1
    ushort* Asw2  = (ushort*)((char*)d_ws + (8u  << 20));  // 4 MB layout-2
    float*  Mpart = (float*)((char*)d_ws + (16u << 20));   // 8 MB gram partials

    row_stats<<<BDIM / 4, 256, 0, stream>>>(anchor, positive, negative, Asw, pt);
    transpose_ahat<<<64, 256, 0, stream>>>(Asw, Asw2);
    gram<<<dim3(32, 2), 256, 0, stream>>>(Asw2, Mpart);
    gram_reduce<<<64, 256, 0, stream>>>(Mpart, gpart);
    s_dot<<<512, 512, 0, stream>>>(S, Asw, Asw2, dotp, s2p);
    finalize<<<1, 256, 0, stream>>>(pt, dotp, s2p, gpart, out);
}

// Round 9
// 355.743 us; speedup vs baseline: 1.2479x; 1.2479x over previous
//
#include <hip/hip_runtime.h>
#include <hip/hip_bf16.h>

#define BDIM 8192
#define DDIM 256

typedef __attribute__((ext_vector_type(8))) short  s16x8;   // 8 x bf16 (4 VGPRs)
typedef __attribute__((ext_vector_type(4))) float  f32x4;   // MFMA accumulator
typedef __attribute__((ext_vector_type(4))) float  fv4;     // clang float4

#define REP16(M) M(0) M(1) M(2) M(3) M(4) M(5) M(6) M(7) \
                 M(8) M(9) M(10) M(11) M(12) M(13) M(14) M(15)

__device__ inline ushort f2bf(float x) {
    __hip_bfloat16 h = __float2bfloat16(x);
    ushort u;
    __builtin_memcpy(&u, &h, 2);
    return u;
}

// ---------------------------------------------------------------------------
// Kernel A: per-row stats + fragment-swizzled bf16 a_hat (layout-1).
//   u16 index(row,d) = (row>>4)*4096 + (d>>5)*512 + ((d>>3)&3)*128
//                      + (row&15)*8 + (d&7)      (verified: absmax 0.0)
// ---------------------------------------------------------------------------
__global__ __launch_bounds__(256) void row_stats(
    const float* __restrict__ A, const float* __restrict__ P,
    const float* __restrict__ N, ushort* __restrict__ Asw,
    float* __restrict__ partial_trip)
{
    __shared__ float tsh[4];
    const int wave = threadIdx.x >> 6;
    const int lane = threadIdx.x & 63;
    const int row  = blockIdx.x * 4 + wave;

    const float4 a = *(reinterpret_cast<const float4*>(A + (size_t)row * DDIM) + lane);
    const float4 p = *(reinterpret_cast<const float4*>(P + (size_t)row * DDIM) + lane);
    const float4 n = *(reinterpret_cast<const float4*>(N + (size_t)row * DDIM) + lane);

    float sa = a.x*a.x + a.y*a.y + a.z*a.z + a.w*a.w;

    float d0 = a.x - p.x + 1e-6f, d1 = a.y - p.y + 1e-6f;
    float d2 = a.z - p.z + 1e-6f, d3 = a.w - p.w + 1e-6f;
    float sp = d0*d0 + d1*d1 + d2*d2 + d3*d3;

    d0 = a.x - n.x + 1e-6f; d1 = a.y - n.y + 1e-6f;
    d2 = a.z - n.z + 1e-6f; d3 = a.w - n.w + 1e-6f;
    float sn = d0*d0 + d1*d1 + d2*d2 + d3*d3;

    #pragma unroll
    for (int off = 32; off > 0; off >>= 1) {
        sa += __shfl_xor(sa, off);
        sp += __shfl_xor(sp, off);
        sn += __shfl_xor(sn, off);
    }

    const float inv = 1.0f / fmaxf(sqrtf(sa), 1e-8f);

    ushort4 hv;
    hv.x = f2bf(a.x * inv);
    hv.y = f2bf(a.y * inv);
    hv.z = f2bf(a.z * inv);
    hv.w = f2bf(a.w * inv);
    const size_t chunk = ((size_t)(row >> 4) * 8 + (lane >> 3)) * 64
                       + (size_t)(((lane >> 1) & 3) * 16 + (row & 15));
    *reinterpret_cast<ushort4*>(Asw + chunk * 8 + (lane & 1) * 4) = hv;

    if (lane == 0)
        tsh[wave] = fmaxf(sqrtf(sp) - sqrtf(sn) + 0.2f, 0.0f);
    __syncthreads();
    if (threadIdx.x == 0)
        partial_trip[blockIdx.x] = tsh[0] + tsh[1] + tsh[2] + tsh[3];
}

// ---------------------------------------------------------------------------
// Kernel T: layout-2 (A_hat^T fragment chunks) from layout-1.
//   u16 base((d0>>4),(j0>>5)) = ((d0>>4)*256 + (j0>>5))*512; lane l holds
//   A_hat[j0 + (l>>4)*8 + jj][d0 + (l&15)], jj=0..7 -> 1KB coalesced frag.
// ---------------------------------------------------------------------------
__global__ __launch_bounds__(256) void transpose_ahat(
    const ushort* __restrict__ Asw, ushort* __restrict__ Asw2)
{
    const int t = threadIdx.x, w = t >> 6, lane = t & 63;
    const int fr = lane & 15, kg = lane >> 4;
    const int b = blockIdx.x;                 // 64 blocks
    const int j0 = b * 128 + w * 32;

    #pragma unroll 1
    for (int D = 0; D < 16; ++D) {
        const int d = D * 16 + fr;
        ushort v[8];
        #pragma unroll
        for (int jj = 0; jj < 8; ++jj) {
            const int J = j0 + kg * 8 + jj;
            v[jj] = Asw[(size_t)(J >> 4) * 4096 + (d >> 5) * 512
                        + ((d >> 3) & 3) * 128 + (J & 15) * 8 + (d & 7)];
        }
        uint4 pk;
        pk.x = v[0] | ((unsigned)v[1] << 16);
        pk.y = v[2] | ((unsigned)v[3] << 16);
        pk.z = v[4] | ((unsigned)v[5] << 16);
        pk.w = v[6] | ((unsigned)v[7] << 16);
        *reinterpret_cast<uint4*>(
            Asw2 + (size_t)(D * 256 + b * 4 + w) * 512 + (size_t)lane * 8) = pk;
    }
}

// ---------------------------------------------------------------------------
// Kernel G: Gram partials  M = A_hat^T A_hat (256x256), K split in 32 chunks.
// ---------------------------------------------------------------------------
__global__ __launch_bounds__(256, 2) void gram(
    const ushort* __restrict__ Asw2, float* __restrict__ Mpart)
{
    const int t = threadIdx.x, w = t >> 6, lane = t & 63;
    const int fr = lane & 15, kg = lane >> 4;
    const int kc = blockIdx.x;   // 0..31
    const int h  = blockIdx.y;   // 0..1

    f32x4 acc[8][4] = {};
    #pragma unroll 1
    for (int k32 = 0; k32 < 8; ++k32) {
        const int j5 = (kc * 256 + k32 * 32) >> 5;
        s16x8 af[8], bf[4];
        #pragma unroll
        for (int m = 0; m < 8; ++m)
            af[m] = *reinterpret_cast<const s16x8*>(
                Asw2 + ((size_t)((h * 8 + m) * 256 + j5)) * 512 + lane * 8);
        #pragma unroll
        for (int n = 0; n < 4; ++n)
            bf[n] = *reinterpret_cast<const s16x8*>(
                Asw2 + ((size_t)((w * 4 + n) * 256 + j5)) * 512 + lane * 8);
        #pragma unroll
        for (int m = 0; m < 8; ++m)
            #pragma unroll
            for (int n = 0; n < 4; ++n)
                acc[m][n] = __builtin_amdgcn_mfma_f32_16x16x32_bf16(
                    af[m], bf[n], acc[m][n], 0, 0, 0);
    }
    float* base = Mpart + (size_t)kc * 65536
                + (size_t)(h * 128 + kg * 4) * 256 + w * 64 + fr;
    #pragma unroll
    for (int m = 0; m < 8; ++m)
        #pragma unroll
        for (int reg = 0; reg < 4; ++reg)
            #pragma unroll
            for (int n = 0; n < 4; ++n)
                base[(size_t)(m * 16 + reg) * 256 + n * 16] = acc[m][n][reg];
}

__global__ __launch_bounds__(256) void gram_reduce(
    const float* __restrict__ Mpart, float* __restrict__ gpart)
{
    __shared__ float sh[4];
    const int t = threadIdx.x;
    const int id = blockIdx.x * 256 + t;
    float ss = 0.f;
    for (int e = id; e < 65536; e += 16384) {
        float s = 0.f;
        #pragma unroll 4
        for (int kc = 0; kc < 32; ++kc)
            s += Mpart[(size_t)kc * 65536 + e];
        ss += s * s;
    }
    #pragma unroll
    for (int off = 32; off > 0; off >>= 1) ss += __shfl_down(ss, off);
    const int w = t >> 6, lane = t & 63;
    if (lane == 0) sh[w] = ss;
    __syncthreads();
    if (t == 0) gpart[blockIdx.x] = sh[0] + sh[1] + sh[2] + sh[3];
}

// ---------------------------------------------------------------------------
// Kernel D (wave-autonomous): trace(A_hat^T S A_hat) partials + sum(S^2).
// 1024 blocks x 256 thr; each of the 4 waves independently owns a 16-row
// i-strip x 1024-col k-chunk. NO LDS, NO barriers, NO NT, NO arrays (16
// named accumulators via macro -> spill-proof by construction).
// Per k-step(32): load S 16x32 f32 (2 fv4/lane, coalesced) -> convert
// in-register to MFMA A-frag -> 16 MFMA vs L2-resident layout-2 frags.
// k-chunk = bid&7 aligns with XCD round-robin -> 512 KB Asw2 slice per L2;
// 4 waves/block share the same fragment stream -> L1 reuse.
// Latency hidden by TLP (~12 waves/CU x ~2 B/cyc >> 10 B/cyc HBM budget).
// ---------------------------------------------------------------------------
__global__ __launch_bounds__(256) void s_dot(
    const float* __restrict__ S, const ushort* __restrict__ Asw,
    const ushort* __restrict__ Asw2,
    float* __restrict__ dotp, float* __restrict__ s2p)
{
    const int t = threadIdx.x;
    const int w = t >> 6, lane = t & 63;
    const int fr = lane & 15, kg = lane >> 4;

    const int bid   = blockIdx.x;             // 0..1023
    const int c0    = (bid & 7) * 1024;       // k-chunk (XCD-aligned)
    const int strip = (bid >> 3) * 4 + w;     // 0..511
    const int i0    = strip * 16;

    // lane's S row = i0 + fr, col base = c0 + kg*8 (+ k32*32 per step)
    const float* sg = S + (size_t)(i0 + fr) * BDIM + c0 + kg * 8;
    // layout-2 frag base for this k-chunk: frag(dt,k32) = bb + dt*131072 + k32*512
    const ushort* bb = Asw2 + (size_t)(c0 >> 5) * 512 + (size_t)lane * 8;

    float s2 = 0.f;

#define DECL_ACC(i) f32x4 ac##i = {0.f, 0.f, 0.f, 0.f};
    REP16(DECL_ACC)
#undef DECL_ACC

    fv4 u = *reinterpret_cast<const fv4*>(sg);
    fv4 v = *reinterpret_cast<const fv4*>(sg + 4);

    for (int k32 = 0; k32 < 32; ++k32) {
        // prefetch next k-step's S
        fv4 un, vn;
        if (k32 < 31) {
            const float* p = sg + (size_t)(k32 + 1) * 32;
            un = *reinterpret_cast<const fv4*>(p);
            vn = *reinterpret_cast<const fv4*>(p + 4);
        }

        // convert current S to bf16 A-frag (lane: row=fr, k=kg*8+0..7)
        s16x8 af;
        af[0] = (short)f2bf(u.x); af[1] = (short)f2bf(u.y);
        af[2] = (short)f2bf(u.z); af[3] = (short)f2bf(u.w);
        af[4] = (short)f2bf(v.x); af[5] = (short)f2bf(v.y);
        af[6] = (short)f2bf(v.z); af[7] = (short)f2bf(v.w);
        s2 += u.x*u.x + u.y*u.y + u.z*u.z + u.w*u.w
            + v.x*v.x + v.y*v.y + v.z*v.z + v.w*v.w;

        const ushort* bp = bb + (size_t)k32 * 512;
#define MF(i) { const s16x8 bf = *reinterpret_cast<const s16x8*>(bp + (size_t)(i) * 131072); \
                ac##i = __builtin_amdgcn_mfma_f32_16x16x32_bf16(af, bf, ac##i, 0, 0, 0); }
        REP16(MF)
#undef MF

        u = un; v = vn;
    }

    // epilogue: dot(acc, A_hat) — C layout: col=fr (d in tile), row=kg*4+reg
    float dot = 0.f;
#define EP(i) { const int d = (i) * 16 + fr;                                   \
                const size_t ab = (size_t)(i0 >> 4) * 4096 + (size_t)(d >> 5) * 512 \
                                + (size_t)((d >> 3) & 3) * 128 + (size_t)(kg * 32) + (d & 7); \
                _Pragma("unroll")                                              \
                for (int reg = 0; reg < 4; ++reg) {                            \
                    const ushort uu = Asw[ab + reg * 8];                       \
                    dot += __uint_as_float((unsigned)uu << 16) * ac##i[reg];   \
                } }
    REP16(EP)
#undef EP

    #pragma unroll
    for (int off = 32; off > 0; off >>= 1) {
        dot += __shfl_down(dot, off);
        s2  += __shfl_down(s2, off);
    }
    if (lane == 0) {
        dotp[bid * 4 + w] = dot;
        s2p[bid * 4 + w]  = s2;
    }
}

// ---------------------------------------------------------------------------
// finalize: out = trip/B + (gram_ss - 2*dot + s2) / B^2
// ---------------------------------------------------------------------------
__global__ __launch_bounds__(256) void finalize(
    const float* __restrict__ pt, const float* __restrict__ dotp,
    const float* __restrict__ s2p, const float* __restrict__ gpart,
    float* __restrict__ out)
{
    __shared__ float sh[4];
    const int t = threadIdx.x;
    float trip = 0.f, sim = 0.f;
    for (int i = t; i < 2048; i += 256) trip += pt[i];
    for (int i = t; i < 4096; i += 256) sim += -2.f * dotp[i] + s2p[i];
    if (t < 64) sim += gpart[t];
    float v = trip * (1.0f / (float)BDIM)
            + sim  * (1.0f / ((float)BDIM * (float)BDIM));
    #pragma unroll
    for (int off = 32; off > 0; off >>= 1) v += __shfl_down(v, off);
    const int w = t >> 6, lane = t & 63;
    if (lane == 0) sh[w] = v;
    __syncthreads();
    if (t == 0) out[0] = sh[0] + sh[1] + sh[2] + sh[3];
}

extern "C" void kernel_launch(void* const* d_in, const int* in_sizes, int n_in,
                              void* d_out, int out_size, void* d_ws, size_t ws_size,
                              hipStream_t stream)
{
    const float* anchor   = (const float*)d_in[0];
    const float* positive = (const float*)d_in[1];
    const float* negative = (const float*)d_in[2];
    const float* S        = (const float*)d_in[3];
    float* out = (float*)d_out;

    float*  pt    = (float*)d_ws;                          // 2048 f
    float*  dotp  = (float*)((char*)d_ws + 8192);          // 4096 f
    float*  s2p   = (float*)((char*)d_ws + 24576);         // 4096 f
    float*  gpart = (float*)((char*)d_ws + 40960);         // 64 f
    ushort* Asw   = (ushort*)((char*)d_ws + (1u  << 20));  // 4 MB layout-1
    ushort* Asw2  = (ushort*)((char*)d_ws + (8u  << 20));  // 4 MB layout-2
    float*  Mpart = (float*)((char*)d_ws + (16u << 20));   // 8 MB gram partials

    row_stats<<<BDIM / 4, 256, 0, stream>>>(anchor, positive, negative, Asw, pt);
    transpose_ahat<<<64, 256, 0, stream>>>(Asw, Asw2);
    gram<<<dim3(32, 2), 256, 0, stream>>>(Asw2, Mpart);
    gram_reduce<<<64, 256, 0, stream>>>(Mpart, gpart);
    s_dot<<<1024, 256, 0, stream>>>(S, Asw, Asw2, dotp, s2p);
    finalize<<<1, 256, 0, stream>>>(pt, dotp, s2p, gpart, out);
}